// Round 1
// 1859.606 us; speedup vs baseline: 1.0102x; 1.0102x over previous
//
#include <hip/hip_runtime.h>
#include <stdint.h>

#define S_LEN  1024
#define DMODEL 1024
#define NH     16
#define HD     64
#define FFDIM  4096
#define VOCAB  32000
#define BATCH  4
#define LAYERS 2
#define MTOT   (BATCH * S_LEN)   // 4096 rows

typedef __bf16 bf16x8 __attribute__((ext_vector_type(8)));
typedef float  f32x4  __attribute__((ext_vector_type(4)));
typedef unsigned short ushort8v __attribute__((ext_vector_type(8)));
typedef unsigned short ushort4v __attribute__((ext_vector_type(4)));
typedef unsigned short u16;

__device__ __forceinline__ u16 f2bf(float f) {
  union { float f; uint32_t u; } c; c.f = f;
  uint32_t u = c.u;
  u += 0x7FFFu + ((u >> 16) & 1u);
  return (u16)(u >> 16);
}

__device__ __forceinline__ f32x4 fzero4() {
  f32x4 z; z[0] = 0.f; z[1] = 0.f; z[2] = 0.f; z[3] = 0.f; return z;
}

// async 16B global->LDS (wave-uniform base + lane*16 contract satisfied by construction)
#define GLD16(gp, lp)                                                                  \
  __builtin_amdgcn_global_load_lds(                                                    \
      (const __attribute__((address_space(1))) unsigned int*)(gp),                     \
      (__attribute__((address_space(3))) unsigned int*)(lp), 16, 0, 0)

// ---------------------------------------------------------------------------
// Weight transpose + fp32->bf16: in [R,C] fp32 -> out [C,R] bf16 (batched via z)
// ---------------------------------------------------------------------------
__global__ __launch_bounds__(256) void transpose_cvt(const float* __restrict__ in,
                                                     u16* __restrict__ out,
                                                     int R, int C) {
  const int64_t boff = (int64_t)blockIdx.z * R * C;
  in += boff; out += boff;
  const int r0 = blockIdx.y * 64, c0 = blockIdx.x * 64;
  __shared__ float tile[64][65];
  const int t = threadIdx.x;
#pragma unroll
  for (int p = 0; p < 4; ++p) {
    int r = p * 16 + (t >> 4);
    int c = (t & 15) * 4;
    float4 v = *(const float4*)(in + (int64_t)(r0 + r) * C + c0 + c);
    tile[r][c] = v.x; tile[r][c + 1] = v.y; tile[r][c + 2] = v.z; tile[r][c + 3] = v.w;
  }
  __syncthreads();
#pragma unroll
  for (int p = 0; p < 4; ++p) {
    int c = p * 16 + (t >> 4);
    int rg = (t & 15) * 4;
    ushort4v o;
    o[0] = f2bf(tile[rg][c]);     o[1] = f2bf(tile[rg + 1][c]);
    o[2] = f2bf(tile[rg + 2][c]); o[3] = f2bf(tile[rg + 3][c]);
    *(ushort4v*)(out + (int64_t)(c0 + c) * R + r0 + rg) = o;
  }
}

// ---------------------------------------------------------------------------
// Embedding: h = tok_emb[x] + pos_emb  -> resid (fp32) + hbf (bf16)
// ---------------------------------------------------------------------------
__global__ __launch_bounds__(256) void embed_kernel(const int* __restrict__ x,
                                                    const float* __restrict__ tok,
                                                    const float* __restrict__ pos,
                                                    float* __restrict__ resid,
                                                    u16* __restrict__ hbf) {
  const int row = blockIdx.x;           // b*S + s
  const int s = row & (S_LEN - 1);
  const int c = threadIdx.x * 4;
  const int id = x[row];
  const float4 tv = *(const float4*)(tok + (int64_t)id * DMODEL + c);
  const float4 pv = *(const float4*)(pos + (int64_t)s * DMODEL + c);
  float4 v; v.x = tv.x + pv.x; v.y = tv.y + pv.y; v.z = tv.z + pv.z; v.w = tv.w + pv.w;
  *(float4*)(resid + (int64_t)row * DMODEL + c) = v;
  ushort4v o; o[0] = f2bf(v.x); o[1] = f2bf(v.y); o[2] = f2bf(v.z); o[3] = f2bf(v.w);
  *(ushort4v*)(hbf + (int64_t)row * DMODEL + c) = o;
}

// ---------------------------------------------------------------------------
// LayerNorm: fp32 in -> fp32 out + bf16 out
// ---------------------------------------------------------------------------
__global__ __launch_bounds__(256) void ln_kernel(const float* __restrict__ xin,
                                                 const float* __restrict__ w,
                                                 const float* __restrict__ bb,
                                                 float* __restrict__ fout,
                                                 u16* __restrict__ bout) {
  const int row = blockIdx.x;
  const int t = threadIdx.x;
  const int c = t * 4;
  const float4 v = *(const float4*)(xin + (int64_t)row * DMODEL + c);
  float s = v.x + v.y + v.z + v.w;
  float sq = v.x * v.x + v.y * v.y + v.z * v.z + v.w * v.w;
#pragma unroll
  for (int off = 1; off < 64; off <<= 1) {
    s += __shfl_xor(s, off);
    sq += __shfl_xor(sq, off);
  }
  __shared__ float red[8];
  if ((t & 63) == 0) { red[t >> 6] = s; red[4 + (t >> 6)] = sq; }
  __syncthreads();
  s = red[0] + red[1] + red[2] + red[3];
  sq = red[4] + red[5] + red[6] + red[7];
  const float mean = s * (1.0f / 1024.0f);
  const float var = sq * (1.0f / 1024.0f) - mean * mean;
  const float rstd = rsqrtf(var + 1e-5f);
  const float4 w4 = *(const float4*)(w + c);
  const float4 b4 = *(const float4*)(bb + c);
  float o0 = (v.x - mean) * rstd * w4.x + b4.x;
  float o1 = (v.y - mean) * rstd * w4.y + b4.y;
  float o2 = (v.z - mean) * rstd * w4.z + b4.z;
  float o3 = (v.w - mean) * rstd * w4.w + b4.w;
  float4 ov; ov.x = o0; ov.y = o1; ov.z = o2; ov.w = o3;
  *(float4*)(fout + (int64_t)row * DMODEL + c) = ov;
  ushort4v ob; ob[0] = f2bf(o0); ob[1] = f2bf(o1); ob[2] = f2bf(o2); ob[3] = f2bf(o3);
  *(ushort4v*)(bout + (int64_t)row * DMODEL + c) = ob;
}

// ---------------------------------------------------------------------------
// GEMM core: C[128,128] tile, A [M,K] bf16 row-major, Bt [N,K] bf16 row-major
// m97 structure: BK=32, global_load_lds(16B), 2-barrier K-loop, 4 waves 4x4 frags
// ---------------------------------------------------------------------------
__device__ __forceinline__ void gemm_core(const u16* __restrict__ A,
                                          const u16* __restrict__ Bt,
                                          int K, int64_t m0, int64_t n0,
                                          u16* As, u16* Bs, f32x4 acc[4][4]) {
  const int t = threadIdx.x;
  const int lane = t & 63;
  const int g = lane >> 4, ln = lane & 15;
  const int wv = t >> 6;
  const int wm = (wv & 1) * 64, wn = (wv >> 1) * 64;

  const u16* ga0 = A + (m0 + (t >> 2)) * (int64_t)K + (t & 3) * 8;
  const u16* ga1 = ga0 + (int64_t)64 * K;
  const u16* gb0 = Bt + (n0 + (t >> 2)) * (int64_t)K + (t & 3) * 8;
  const u16* gb1 = gb0 + (int64_t)64 * K;
  u16* la0 = As + t * 8;
  u16* la1 = As + 2048 + t * 8;
  u16* lb0 = Bs + t * 8;
  u16* lb1 = Bs + 2048 + t * 8;

  const int nk = K >> 5;
  for (int kt = 0; kt < nk; ++kt) {
    if (kt) __syncthreads();
    GLD16(ga0, la0); GLD16(ga1, la1);
    GLD16(gb0, lb0); GLD16(gb1, lb1);
    ga0 += 32; ga1 += 32; gb0 += 32; gb1 += 32;
    __syncthreads();          // drains vmcnt: LDS data ready
    bf16x8 af[4], bfr[4];
#pragma unroll
    for (int i = 0; i < 4; ++i)
      af[i] = *(const bf16x8*)(As + (wm + i * 16 + ln) * 32 + g * 8);
#pragma unroll
    for (int j = 0; j < 4; ++j)
      bfr[j] = *(const bf16x8*)(Bs + (wn + j * 16 + ln) * 32 + g * 8);
#pragma unroll
    for (int i = 0; i < 4; ++i)
#pragma unroll
      for (int j = 0; j < 4; ++j)
        acc[i][j] = __builtin_amdgcn_mfma_f32_16x16x32_bf16(af[i], bfr[j], acc[i][j], 0, 0, 0);
  }
}

// MODE 0: bias -> bf16   MODE 1: bias+GELU -> bf16
// MODE 2: bias+resid -> f32    MODE 3: bias -> f32
template <int MODE>
__device__ __forceinline__ void gemm_epi(f32x4 acc[4][4], const float* __restrict__ bias,
                                         const float* __restrict__ resid,
                                         float* __restrict__ outf, u16* __restrict__ outb,
                                         int64_t m0, int64_t n0, int N) {
  const int t = threadIdx.x;
  const int lane = t & 63, wv = t >> 6;
  const int g = lane >> 4, ln = lane & 15;
  const int64_t wmb = m0 + (wv & 1) * 64;
  const int64_t wnb = n0 + (wv >> 1) * 64;
#pragma unroll
  for (int j = 0; j < 4; ++j) {
    const int64_t col = wnb + j * 16 + ln;
    const float bj = bias[col];
#pragma unroll
    for (int i = 0; i < 4; ++i) {
#pragma unroll
      for (int r = 0; r < 4; ++r) {
        const int64_t row = wmb + i * 16 + g * 4 + r;
        const int64_t idx = row * (int64_t)N + col;
        float v = acc[i][j][r] + bj;
        if (MODE == 1) v = 0.5f * v * (1.0f + erff(v * 0.70710678118f));
        if (MODE == 2) v += resid[idx];
        if (MODE <= 1) outb[idx] = f2bf(v);
        else           outf[idx] = v;
      }
    }
  }
}

// REMAP=1: chunk-major + XCD-bijective block order for the logits GEMM
// (grid MUST be dim3(250,32)). Mechanism: default N-fastest order streams the
// whole 65.5 MB B through L3 every ~3 M-rows while 536 MB of output writes
// evict it -> B re-fetched ~16x from HBM (measured FETCH 1.17 GB). Chunk-major
// order processes ALL 32 M-tiles of a 25-N-tile chunk (800 blocks = one
// co-resident generation; B-chunk 6.5 MB) before advancing, and the XCD
// swizzle gives each of the 8 XCDs a contiguous sub-range (~3 N-tiles, 800 KB
// of B -> L2-resident, no cross-L2 duplication). B then leaves HBM once.
template <int MODE, int REMAP>
__global__ __launch_bounds__(256) void gemm_kernel(const u16* __restrict__ A,
                                                   const u16* __restrict__ Bt,
                                                   const float* __restrict__ bias,
                                                   const float* __restrict__ resid,
                                                   float* __restrict__ outf,
                                                   u16* __restrict__ outb,
                                                   int K, int N) {
  __shared__ u16 As[4096];
  __shared__ u16 Bs[4096];
  f32x4 acc[4][4];
#pragma unroll
  for (int i = 0; i < 4; ++i)
#pragma unroll
    for (int j = 0; j < 4; ++j) acc[i][j] = fzero4();
  int bxi = blockIdx.x, byi = blockIdx.y;
  if (REMAP) {
    // bijection: lid in [0,8000) -> chunk in [0,10) x within in [0,800)
    //   w2 = (within&7)*100 + within>>3   (XCD-contiguous, 800%8==0)
    //   m = w2&31 (M-fastest), i = w2>>5 in [0,25)
    const int lid = byi * 250 + bxi;
    const int chunk = lid / 800;
    const int within = lid - chunk * 800;
    const int w2 = (within & 7) * 100 + (within >> 3);
    byi = w2 & 31;
    bxi = chunk * 25 + (w2 >> 5);
  }
  const int64_t m0 = (int64_t)byi * 128;
  const int64_t n0 = (int64_t)bxi * 128;
  gemm_core(A, Bt, K, m0, n0, As, Bs, acc);
  gemm_epi<MODE>(acc, bias, resid, outf, outb, m0, n0, N);
}

// fused q/k/v projection: blockIdx.z selects weight/bias/output
__global__ __launch_bounds__(256) void gemm_qkv_kernel(const u16* __restrict__ A,
    const u16* __restrict__ btq, const u16* __restrict__ btk, const u16* __restrict__ btv,
    const float* __restrict__ bq, const float* __restrict__ bk, const float* __restrict__ bv,
    u16* __restrict__ oq, u16* __restrict__ ok, u16* __restrict__ ov) {
  const int z = blockIdx.z;
  const u16* Bt = (z == 0) ? btq : (z == 1) ? btk : btv;
  const float* bias = (z == 0) ? bq : (z == 1) ? bk : bv;
  u16* ob = (z == 0) ? oq : (z == 1) ? ok : ov;
  __shared__ u16 As[4096];
  __shared__ u16 Bs[4096];
  f32x4 acc[4][4];
#pragma unroll
  for (int i = 0; i < 4; ++i)
#pragma unroll
    for (int j = 0; j < 4; ++j) acc[i][j] = fzero4();
  const int64_t m0 = (int64_t)blockIdx.y * 128;
  const int64_t n0 = (int64_t)blockIdx.x * 128;
  gemm_core(A, Bt, DMODEL, m0, n0, As, Bs, acc);
  gemm_epi<0>(acc, bias, nullptr, nullptr, ob, m0, n0, DMODEL);
}

// ---------------------------------------------------------------------------
// V transpose: vb [B,S,D] (col h*64+d) -> vt [B,H,64,S]
// ---------------------------------------------------------------------------
__global__ __launch_bounds__(256) void transpose_v_kernel(const u16* __restrict__ vb,
                                                          u16* __restrict__ vt) {
  const int bh = blockIdx.y;     // b*16 + h
  const int b = bh >> 4, h = bh & 15;
  const int s0 = blockIdx.x * 64;
  const int t = threadIdx.x;
  __shared__ u16 tile[64][80];   // [s][d], stride 80 keeps 16B alignment
#pragma unroll
  for (int p = 0; p < 2; ++p) {
    int sr = p * 32 + (t >> 3);
    int c = (t & 7) * 8;
    ushort8v v = *(const ushort8v*)(vb + ((int64_t)(b * S_LEN + s0 + sr)) * DMODEL + h * HD + c);
    *(ushort8v*)(&tile[sr][c]) = v;
  }
  __syncthreads();
#pragma unroll
  for (int p = 0; p < 2; ++p) {
    int d = p * 32 + (t >> 3);
    int sg = (t & 7) * 8;
    ushort8v o;
#pragma unroll
    for (int j = 0; j < 8; ++j) o[j] = tile[sg + j][d];
    *(ushort8v*)(vt + ((int64_t)(bh * HD + d)) * S_LEN + s0 + sg) = o;
  }
}

// ---------------------------------------------------------------------------
// Flash attention: 1 block per (q-64-block, head, batch); 4 waves x 16 q-rows
// ---------------------------------------------------------------------------
__global__ __launch_bounds__(256) void attn_kernel(const u16* __restrict__ qb,
                                                   const u16* __restrict__ kb,
                                                   const u16* __restrict__ vt,
                                                   u16* __restrict__ ob) {
  const int qblk = blockIdx.x, h = blockIdx.y, b = blockIdx.z;
  const int t = threadIdx.x;
  const int wv = t >> 6, lane = t & 63;
  const int g = lane >> 4, ln = lane & 15;
  __shared__ u16 Ks[32 * 64];    // [key][hd]
  __shared__ u16 Vts[64 * 32];   // [hd][key]
  __shared__ u16 Ps[4][16 * 40]; // per-wave P, row stride 40 (80B, 16B-aligned)
  const int q0 = qblk * 64;

  const u16* qptr = qb + ((int64_t)(b * S_LEN + q0 + wv * 16 + ln)) * DMODEL + h * HD;
  const bf16x8 qf0 = *(const bf16x8*)(qptr + g * 8);
  const bf16x8 qf1 = *(const bf16x8*)(qptr + 32 + g * 8);

  f32x4 oo[4];
  float m_i[4], l_i[4];
#pragma unroll
  for (int r = 0; r < 4; ++r) { oo[r] = fzero4(); m_i[r] = -1e30f; l_i[r] = 0.f; }

  const int ntiles = (q0 >> 5) + 2;
  const u16* kbase = kb + ((int64_t)(b * S_LEN)) * DMODEL + h * HD;
  const u16* vbase = vt + ((int64_t)((b * NH + h) * HD)) * S_LEN;

  for (int kt = 0; kt < ntiles; ++kt) {
    const int k0 = kt * 32;
    if (kt) __syncthreads();
    // stage K tile [32][64] and Vt tile [64][32]
    GLD16(kbase + (int64_t)(k0 + (t >> 3)) * DMODEL + (t & 7) * 8, &Ks[t * 8]);
    GLD16(vbase + (int64_t)(t >> 2) * S_LEN + k0 + (t & 3) * 8, &Vts[t * 8]);
    __syncthreads();

    // QK^T: 16 q-rows x 32 keys
    f32x4 s0 = fzero4(), s1 = fzero4();
    {
      bf16x8 ka = *(const bf16x8*)(&Ks[ln * 64 + g * 8]);
      bf16x8 kbf = *(const bf16x8*)(&Ks[ln * 64 + 32 + g * 8]);
      s0 = __builtin_amdgcn_mfma_f32_16x16x32_bf16(qf0, ka, s0, 0, 0, 0);
      s0 = __builtin_amdgcn_mfma_f32_16x16x32_bf16(qf1, kbf, s0, 0, 0, 0);
      bf16x8 kc = *(const bf16x8*)(&Ks[(16 + ln) * 64 + g * 8]);
      bf16x8 kd = *(const bf16x8*)(&Ks[(16 + ln) * 64 + 32 + g * 8]);
      s1 = __builtin_amdgcn_mfma_f32_16x16x32_bf16(qf0, kc, s1, 0, 0, 0);
      s1 = __builtin_amdgcn_mfma_f32_16x16x32_bf16(qf1, kd, s1, 0, 0, 0);
    }
    // online softmax, C-layout: row = g*4 + r, col = ln
#pragma unroll
    for (int r = 0; r < 4; ++r) {
      const int qg = q0 + wv * 16 + g * 4 + r;
      float sc0 = s0[r] * 0.125f;
      float sc1 = s1[r] * 0.125f;
      if (k0 + ln > qg)      sc0 = -1e30f;
      if (k0 + 16 + ln > qg) sc1 = -1e30f;
      float mx = fmaxf(sc0, sc1);
#pragma unroll
      for (int off = 1; off < 16; off <<= 1) mx = fmaxf(mx, __shfl_xor(mx, off));
      const float mnew = fmaxf(m_i[r], mx);
      const float p0 = __expf(sc0 - mnew);
      const float p1 = __expf(sc1 - mnew);
      float rs = p0 + p1;
#pragma unroll
      for (int off = 1; off < 16; off <<= 1) rs += __shfl_xor(rs, off);
      const float alpha = __expf(m_i[r] - mnew);
      l_i[r] = l_i[r] * alpha + rs;
      m_i[r] = mnew;
      oo[0][r] *= alpha; oo[1][r] *= alpha; oo[2][r] *= alpha; oo[3][r] *= alpha;
      Ps[wv][(g * 4 + r) * 40 + ln] = f2bf(p0);
      Ps[wv][(g * 4 + r) * 40 + 16 + ln] = f2bf(p1);
    }
    __threadfence_block();  // order Ps writes before A-frag reads (same wave)
    // PV: P [16 q x 32 keys] (A-layout from LDS) x V [32 keys x 64 dims]
    const bf16x8 pf = *(const bf16x8*)(&Ps[wv][ln * 40 + g * 8]);
#pragma unroll
    for (int j = 0; j < 4; ++j) {
      bf16x8 vf = *(const bf16x8*)(&Vts[(j * 16 + ln) * 32 + g * 8]);
      oo[j] = __builtin_amdgcn_mfma_f32_16x16x32_bf16(pf, vf, oo[j], 0, 0, 0);
    }
  }
  // normalize + store bf16 at [b,s, h*64 + d]
#pragma unroll
  for (int r = 0; r < 4; ++r) {
    const float inv = 1.0f / l_i[r];
    const int64_t row = (int64_t)(b * S_LEN + q0 + wv * 16 + g * 4 + r);
#pragma unroll
    for (int j = 0; j < 4; ++j)
      ob[row * DMODEL + h * HD + j * 16 + ln] = f2bf(oo[j][r] * inv);
  }
}

// ---------------------------------------------------------------------------
// Host launcher
// ---------------------------------------------------------------------------
extern "C" void kernel_launch(void* const* d_in, const int* in_sizes, int n_in,
                              void* d_out, int out_size, void* d_ws, size_t ws_size,
                              hipStream_t stream) {
  const int*   x    = (const int*)d_in[0];
  const float* tok  = (const float*)d_in[1];
  const float* pos  = (const float*)d_in[2];
  const float* Wq   = (const float*)d_in[3];
  const float* bq   = (const float*)d_in[4];
  const float* Wk   = (const float*)d_in[5];
  const float* bk   = (const float*)d_in[6];
  const float* Wv   = (const float*)d_in[7];
  const float* bv   = (const float*)d_in[8];
  const float* Wo   = (const float*)d_in[9];
  const float* bo   = (const float*)d_in[10];
  const float* ln1w = (const float*)d_in[11];
  const float* ln1b = (const float*)d_in[12];
  const float* ln2w = (const float*)d_in[13];
  const float* ln2b = (const float*)d_in[14];
  const float* W1   = (const float*)d_in[15];
  const float* b1   = (const float*)d_in[16];
  const float* W2   = (const float*)d_in[17];
  const float* b2   = (const float*)d_in[18];
  const float* Wout = (const float*)d_in[19];
  const float* bout = (const float*)d_in[20];

  float* outF = (float*)d_out;
  float* hOut = outF + (int64_t)MTOT * VOCAB;  // h chunk of the tuple output

  // workspace carve-up (bytes)
  char* ws = (char*)d_ws;
  int64_t off = 0;
  auto carve = [&](int64_t bytes) { char* p = ws + off; off += (bytes + 255) & ~255LL; return p; };
  u16* wqT   = (u16*)carve((int64_t)LAYERS * DMODEL * DMODEL * 2);
  u16* wkT   = (u16*)carve((int64_t)LAYERS * DMODEL * DMODEL * 2);
  u16* wvT   = (u16*)carve((int64_t)LAYERS * DMODEL * DMODEL * 2);
  u16* woT   = (u16*)carve((int64_t)LAYERS * DMODEL * DMODEL * 2);
  u16* w1T   = (u16*)carve((int64_t)LAYERS * FFDIM * DMODEL * 2);
  u16* w2T   = (u16*)carve((int64_t)LAYERS * DMODEL * FFDIM * 2);
  u16* woutT = (u16*)carve((int64_t)VOCAB * DMODEL * 2);
  u16* hbf   = (u16*)carve((int64_t)MTOT * DMODEL * 2);
  u16* qbuf  = (u16*)carve((int64_t)MTOT * DMODEL * 2);
  u16* kbuf  = (u16*)carve((int64_t)MTOT * DMODEL * 2);
  u16* vbuf  = (u16*)carve((int64_t)MTOT * DMODEL * 2);
  u16* vtb   = (u16*)carve((int64_t)MTOT * DMODEL * 2);
  u16* abuf  = (u16*)carve((int64_t)MTOT * DMODEL * 2);
  u16* ffb   = (u16*)carve((int64_t)MTOT * FFDIM * 2);
  float* resid = (float*)carve((int64_t)MTOT * DMODEL * 4);
  float* x1    = (float*)carve((int64_t)MTOT * DMODEL * 4);

  const dim3 blk(256);

  // weight conversion + transpose (every launch; harness re-poisons ws)
  transpose_cvt<<<dim3(1, 16, LAYERS * NH), blk, 0, stream>>>(Wq, wqT, DMODEL, HD);
  transpose_cvt<<<dim3(1, 16, LAYERS * NH), blk, 0, stream>>>(Wk, wkT, DMODEL, HD);
  transpose_cvt<<<dim3(1, 16, LAYERS * NH), blk, 0, stream>>>(Wv, wvT, DMODEL, HD);
  transpose_cvt<<<dim3(16, 16, LAYERS), blk, 0, stream>>>(Wo, woT, DMODEL, DMODEL);
  transpose_cvt<<<dim3(64, 16, LAYERS), blk, 0, stream>>>(W1, w1T, DMODEL, FFDIM);
  transpose_cvt<<<dim3(16, 64, LAYERS), blk, 0, stream>>>(W2, w2T, FFDIM, DMODEL);
  transpose_cvt<<<dim3(500, 16, 1), blk, 0, stream>>>(Wout, woutT, DMODEL, VOCAB);

  embed_kernel<<<MTOT, blk, 0, stream>>>(x, tok, pos, resid, hbf);

  for (int l = 0; l < LAYERS; ++l) {
    const int64_t wOff  = (int64_t)l * DMODEL * DMODEL;
    const int64_t w1Off = (int64_t)l * FFDIM * DMODEL;
    gemm_qkv_kernel<<<dim3(8, 32, 3), blk, 0, stream>>>(
        hbf, wqT + wOff, wkT + wOff, wvT + wOff,
        bq + l * DMODEL, bk + l * DMODEL, bv + l * DMODEL, qbuf, kbuf, vbuf);
    transpose_v_kernel<<<dim3(16, 64), blk, 0, stream>>>(vbuf, vtb);
    attn_kernel<<<dim3(16, 16, 4), blk, 0, stream>>>(qbuf, kbuf, vtb, abuf);
    gemm_kernel<2, 0><<<dim3(8, 32), blk, 0, stream>>>(
        abuf, woT + wOff, bo + l * DMODEL, resid, x1, nullptr, DMODEL, DMODEL);
    ln_kernel<<<MTOT, blk, 0, stream>>>(x1, ln1w + l * DMODEL, ln1b + l * DMODEL, resid, hbf);
    gemm_kernel<1, 0><<<dim3(32, 32), blk, 0, stream>>>(
        hbf, w1T + w1Off, b1 + l * FFDIM, nullptr, nullptr, ffb, DMODEL, FFDIM);
    gemm_kernel<2, 0><<<dim3(8, 32), blk, 0, stream>>>(
        ffb, w2T + w1Off, b2 + l * DMODEL, resid, x1, nullptr, FFDIM, DMODEL);
    float* lnout = (l == LAYERS - 1) ? hOut : resid;
    ln_kernel<<<MTOT, blk, 0, stream>>>(x1, ln2w + l * DMODEL, ln2b + l * DMODEL, lnout, hbf);
  }

  gemm_kernel<3, 1><<<dim3(250, 32), blk, 0, stream>>>(
      hbf, woutT, bout, nullptr, outF, nullptr, DMODEL, VOCAB);
}